// Round 7
// baseline (601.898 us; speedup 1.0000x reference)
//
#include <hip/hip_runtime.h>
#include <hip/hip_bf16.h>
#include <math.h>

// Problem constants (B=2, C=256, H=W=64, D=4, K=9, K2=81)
#define BATCH 2
#define CCH   256
#define HH    64
#define WW    64
#define PIX   (HH*WW)          // 4096
#define K2    81
#define BP_N  (BATCH*PIX)      // 8192

// ---------------------------------------------------------------------------
// NCHW -> NHWC tiled transpose (per batch).  in: [B][C][P]  out: [B][P][C]
// ---------------------------------------------------------------------------
__global__ void k_transpose(const float* __restrict__ in, float* __restrict__ out) {
    __shared__ float tile[32][33];
    int b  = blockIdx.z;
    int p0 = blockIdx.x * 32;
    int c0 = blockIdx.y * 32;
    int tx = threadIdx.x;     // 32
    int ty = threadIdx.y;     // 8
    const float* ib = in  + (size_t)b * CCH * PIX;
    float*       ob = out + (size_t)b * CCH * PIX;
    #pragma unroll
    for (int i = 0; i < 4; i++) {
        int c = c0 + ty + i * 8;
        int p = p0 + tx;
        tile[ty + i * 8][tx] = ib[(size_t)c * PIX + p];
    }
    __syncthreads();
    #pragma unroll
    for (int i = 0; i < 4; i++) {
        int p = p0 + ty + i * 8;
        int c = c0 + tx;
        ob[(size_t)p * CCH + c] = tile[tx][ty + i * 8];
    }
}

// ---------------------------------------------------------------------------
// Correlation + sum-normalize + assemble, replicating the np reference's
// fp32 order.  Phase 1 (aff[k] dot over c=256): SIMD-reduction pattern
// (VF=8, 4 interleaved accumulators = 32 strided FMA partials, tree combine
// (v0+v1)+(v2+v3), shuffle-halves horizontal reduce) — the LLVM/npyv idiom
// for an AVX2 fp32 dot.  Phase 2: sequential ascending-k fp32 adds (numpy
// strided reduce / XLA reduce both do this).  fp32 divide.  Phase 3:
// sequential ascending-k FMA (its rounding is negligible: ~5 abs vs 4096 ULP).
// The normalizer 1/(sum+1e-7) is catastrophically ill-conditioned at one
// pixel (|aligned| ~ 1e6); downstream softmax saturates there so out ==
// aligned — the corr path is the entire error budget.
// ---------------------------------------------------------------------------
__global__ void k_corr_assemble(const float* __restrict__ featT,
                                const float* __restrict__ refT,
                                float* __restrict__ alignedT,
                                float* __restrict__ alignedN) {
    int bp = blockIdx.x;               // 0..8191
    int b  = bp >> 12;
    int p  = bp & 4095;
    int h  = p >> 6, w = p & 63;
    int tid = threadIdx.x;             // 0..255

    __shared__ float s_feat[256];
    __shared__ float s_aff[K2];
    __shared__ float s_affn[K2];
    __shared__ int   s_pix[K2];
    __shared__ float s_den;

    s_feat[tid] = featT[((size_t)bp << 8) + tid];
    if (tid < K2) {
        int dy = tid / 9, dx = tid - dy * 9;
        int y = h + dy - 4, x = w + dx - 4;
        s_pix[tid] = ((unsigned)y < 64u && (unsigned)x < 64u) ? ((y << 6) | x) : -1;
    }
    __syncthreads();

    const float* rb = refT + ((size_t)b << 20);   // b*4096*256

    // Phase 1: aff[k] via 32 strided FMA partials + tree/horizontal combine
    if (tid < K2) {
        float aff = 0.f;
        int pix = s_pix[tid];
        if (pix >= 0) {
            const float* rp = rb + ((size_t)pix << 8);
            float acc[4][8];
            #pragma unroll
            for (int m = 0; m < 4; m++)
                #pragma unroll
                for (int l = 0; l < 8; l++) acc[m][l] = 0.f;
            for (int i = 0; i < 256; i += 32) {
                #pragma unroll
                for (int m = 0; m < 4; m++)
                    #pragma unroll
                    for (int l = 0; l < 8; l++) {
                        int c = i + 8 * m + l;
                        acc[m][l] = fmaf(s_feat[c], rp[c], acc[m][l]);
                    }
            }
            // tree combine of the 4 vector accumulators: (v0+v1)+(v2+v3)
            float v[8];
            #pragma unroll
            for (int l = 0; l < 8; l++)
                v[l] = __fadd_rn(__fadd_rn(acc[0][l], acc[1][l]),
                                 __fadd_rn(acc[2][l], acc[3][l]));
            // horizontal shuffle-halves reduce: (l,l+4) -> (l,l+2) -> (l,l+1)
            float s4[4], s2[2];
            #pragma unroll
            for (int l = 0; l < 4; l++) s4[l] = __fadd_rn(v[l], v[l + 4]);
            s2[0] = __fadd_rn(s4[0], s4[2]);
            s2[1] = __fadd_rn(s4[1], s4[3]);
            aff = __fadd_rn(s2[0], s2[1]);
        }
        s_aff[tid] = aff;
    }
    __syncthreads();

    // Phase 2: s = sequential ascending-k fp32 add chain; den = s + 1e-7f
    if (tid == 0) {
        float s = 0.f;
        for (int k = 0; k < K2; k++) s = __fadd_rn(s, s_aff[k]);
        s_den = __fadd_rn(s, 1e-7f);
    }
    __syncthreads();
    if (tid < K2) s_affn[tid] = __fdiv_rn(s_aff[tid], s_den);
    __syncthreads();

    // Phase 3: aligned[c] = sequential ascending-k FMA chain
    int c = tid;
    float acc = 0.f;
    for (int k = 0; k < K2; k++) {
        int pix = s_pix[k];
        if (pix >= 0)
            acc = fmaf(s_affn[k], rb[((size_t)pix << 8) + c], acc);
    }
    alignedT[((size_t)bp << 8) + c] = acc;
    alignedN[((size_t)b << 20) + ((size_t)c << 12) + p] = acc;
}

// ---------------------------------------------------------------------------
// Conv1: 1x1, 512 -> 256, FP32, sequential ascending-c FMA chain, bias at end.
// h1: [BP][256] fp32.
// ---------------------------------------------------------------------------
__global__ void k_conv1(const float* __restrict__ featT,
                        const float* __restrict__ alignedT,
                        const float* __restrict__ w1,
                        const float* __restrict__ b1,
                        float* __restrict__ h1) {
    __shared__ float s_cat[8][512];
    int p0  = blockIdx.x * 8;
    int tid = threadIdx.x;

    for (int i = tid; i < 8 * 512; i += 256) {
        int px = i >> 9;
        int c  = i & 511;
        size_t gp = (size_t)(p0 + px);
        s_cat[px][c] = (c < 256) ? featT[(gp << 8) + c] : alignedT[(gp << 8) + (c - 256)];
    }
    __syncthreads();

    int o = tid;
    float acc[8];
    #pragma unroll
    for (int px = 0; px < 8; px++) acc[px] = 0.f;

    const float* wr = w1 + (size_t)o * 512;
    for (int c = 0; c < 512; c += 4) {
        float4 wv = *(const float4*)(wr + c);
        #pragma unroll
        for (int px = 0; px < 8; px++) {
            float a = acc[px];
            a = fmaf(wv.x, s_cat[px][c + 0], a);
            a = fmaf(wv.y, s_cat[px][c + 1], a);
            a = fmaf(wv.z, s_cat[px][c + 2], a);
            a = fmaf(wv.w, s_cat[px][c + 3], a);
            acc[px] = a;
        }
    }
    float bias = b1[o];
    for (int px = 0; px < 8; px++)
        h1[((size_t)(p0 + px) << 8) + o] = __fadd_rn(acc[px], bias);
}

// ---------------------------------------------------------------------------
// w2 [16][256][3][3] (o,c,kk) -> w2t [c][kk][o]
// ---------------------------------------------------------------------------
__global__ void k_w2t(const float* __restrict__ w2, float* __restrict__ w2t) {
    int i = blockIdx.x * 256 + threadIdx.x;
    if (i >= 16 * 256 * 9) return;
    int o = i / 2304;
    int r = i % 2304;          // c*9 + kk
    w2t[r * 16 + o] = w2[i];
}

// ---------------------------------------------------------------------------
// Conv2: 3x3 pad1, 256 -> 16, FP32, ascending (c,ky,kx) FMA, bias at end.
// ---------------------------------------------------------------------------
__global__ void k_conv2(const float* __restrict__ h1,
                        const float* __restrict__ w2t,
                        const float* __restrict__ b2,
                        float* __restrict__ h2) {
    int idx = blockIdx.x * 256 + threadIdx.x;   // bp*16 + o
    int o  = idx & 15;
    int bp = idx >> 4;
    int b  = bp >> 12;
    int p  = bp & 4095;
    int h  = p >> 6, w = p & 63;
    const float* hb = h1 + ((size_t)b << 20);

    const float* nb[9];
    #pragma unroll
    for (int kk = 0; kk < 9; kk++) {
        int ky = kk / 3, kx = kk - ky * 3;
        int y = h + ky - 1, x = w + kx - 1;
        nb[kk] = ((unsigned)y < 64u && (unsigned)x < 64u)
               ? hb + ((size_t)((y << 6) | x) << 8) : nullptr;
    }

    float acc = 0.f;
    const float* wp = w2t + o;                   // [c][kk][o], stride 16 over kk
    for (int c = 0; c < 256; c++) {
        #pragma unroll
        for (int kk = 0; kk < 9; kk++) {
            if (nb[kk])
                acc = fmaf(wp[kk * 16], nb[kk][c], acc);
        }
        wp += 144;                                // 9*16
    }
    h2[(size_t)bp * 16 + o] = __fadd_rn(acc, b2[o]);
}

// ---------------------------------------------------------------------------
// Conv3: 3x3 pad1, 16 -> 3, FP32, ascending (c,ky,kx) FMA, bias at end.
// ---------------------------------------------------------------------------
__global__ void k_conv3(const float* __restrict__ h2,
                        const float* __restrict__ w3,
                        const float* __restrict__ b3,
                        float* __restrict__ h3) {
    int bp = blockIdx.x * 256 + threadIdx.x;
    if (bp >= BP_N) return;
    int b = bp >> 12;
    int p = bp & 4095;
    int h = p >> 6, w = p & 63;
    const float* hb = h2 + ((size_t)b << 16);   // b*4096*16

    const float* nb[9];
    #pragma unroll
    for (int kk = 0; kk < 9; kk++) {
        int ky = kk / 3, kx = kk - ky * 3;
        int y = h + ky - 1, x = w + kx - 1;
        nb[kk] = ((unsigned)y < 64u && (unsigned)x < 64u)
               ? hb + (size_t)((y << 6) | x) * 16 : nullptr;
    }

    float a0 = 0.f, a1 = 0.f, a2 = 0.f;
    for (int c = 0; c < 16; c++) {
        #pragma unroll
        for (int kk = 0; kk < 9; kk++) {
            if (nb[kk]) {
                float v = nb[kk][c];
                int wi = c * 9 + kk;
                a0 = fmaf(w3[wi],       v, a0);
                a1 = fmaf(w3[144 + wi], v, a1);
                a2 = fmaf(w3[288 + wi], v, a2);
            }
        }
    }
    h3[(size_t)bp * 3 + 0] = __fadd_rn(a0, b3[0]);
    h3[(size_t)bp * 3 + 1] = __fadd_rn(a1, b3[1]);
    h3[(size_t)bp * 3 + 2] = __fadd_rn(a2, b3[2]);
}

// ---------------------------------------------------------------------------
// Conv4 (3x3, 3 -> 2) + softmax -> (score0, score1), FP32.
// ---------------------------------------------------------------------------
__global__ void k_score(const float* __restrict__ h3,
                        const float* __restrict__ w4,
                        const float* __restrict__ b4,
                        float2* __restrict__ score) {
    int bp = blockIdx.x * 256 + threadIdx.x;
    if (bp >= BP_N) return;
    int b = bp >> 12;
    int p = bp & 4095;
    int h = p >> 6, w = p & 63;
    const float* hb = h3 + (size_t)b * PIX * 3;

    const float* nb[9];
    #pragma unroll
    for (int kk = 0; kk < 9; kk++) {
        int ky = kk / 3, kx = kk - ky * 3;
        int y = h + ky - 1, x = w + kx - 1;
        nb[kk] = ((unsigned)y < 64u && (unsigned)x < 64u)
               ? hb + (size_t)((y << 6) | x) * 3 : nullptr;
    }

    float l0 = 0.f, l1 = 0.f;
    for (int c = 0; c < 3; c++) {
        #pragma unroll
        for (int kk = 0; kk < 9; kk++) {
            if (nb[kk]) {
                float v = nb[kk][c];
                int wi = c * 9 + kk;
                l0 = fmaf(w4[wi],      v, l0);
                l1 = fmaf(w4[27 + wi], v, l1);
            }
        }
    }
    l0 = __fadd_rn(l0, b4[0]);
    l1 = __fadd_rn(l1, b4[1]);

    float m  = fmaxf(l0, l1);
    float e0 = expf(__fsub_rn(l0, m));
    float e1 = expf(__fsub_rn(l1, m));
    float s  = __fadd_rn(e0, e1);
    score[bp] = make_float2(__fdiv_rn(e0, s), __fdiv_rn(e1, s));
}

// ---------------------------------------------------------------------------
// Blend: out = s0*feat + s1*aligned.
// ---------------------------------------------------------------------------
__global__ void k_blend(const float* __restrict__ feat,
                        const float* __restrict__ alignedN,
                        const float2* __restrict__ score,
                        float* __restrict__ out) {
    size_t i = (size_t)blockIdx.x * 256 + threadIdx.x;
    if (i >= (size_t)BATCH * CCH * PIX) return;
    int b = (int)(i >> 20);       // 256*4096 = 2^20
    int p = (int)(i & 4095);
    float2 s = score[(b << 12) + p];
    out[i] = __fadd_rn(__fmul_rn(s.x, feat[i]), __fmul_rn(s.y, alignedN[i]));
}

// ---------------------------------------------------------------------------
extern "C" void kernel_launch(void* const* d_in, const int* in_sizes, int n_in,
                              void* d_out, int out_size, void* d_ws, size_t ws_size,
                              hipStream_t stream) {
    const float* feat     = (const float*)d_in[0];
    const float* feat_ref = (const float*)d_in[1];
    const float* w1 = (const float*)d_in[2];
    const float* b1 = (const float*)d_in[3];
    const float* w2 = (const float*)d_in[4];
    const float* b2 = (const float*)d_in[5];
    const float* w3 = (const float*)d_in[6];
    const float* b3 = (const float*)d_in[7];
    const float* w4 = (const float*)d_in[8];
    const float* b4 = (const float*)d_in[9];
    float* out = (float*)d_out;

    const size_t NCP = (size_t)BATCH * CCH * PIX;   // 2,097,152
    char* wsb = (char*)d_ws;
    float*  featT    = (float*)wsb;   wsb += NCP * 4;               // 8 MB
    float*  refT     = (float*)wsb;   wsb += NCP * 4;               // 8 MB
    float*  alignedT = (float*)wsb;   wsb += NCP * 4;               // 8 MB
    float*  alignedN = (float*)wsb;   wsb += NCP * 4;               // 8 MB
    float*  h1       = (float*)wsb;   wsb += NCP * 4;               // 8 MB
    float*  h2       = (float*)wsb;   wsb += (size_t)BP_N * 16 * 4;
    float*  h3       = (float*)wsb;   wsb += (size_t)BP_N * 3 * 4;
    float2* sc       = (float2*)wsb;  wsb += (size_t)BP_N * 8;
    float*  w2t      = (float*)wsb;   wsb += (size_t)16 * 256 * 9 * 4;

    dim3 tb(32, 8, 1);
    dim3 tg(PIX / 32, CCH / 32, BATCH);
    k_transpose<<<tg, tb, 0, stream>>>(feat, featT);
    k_transpose<<<tg, tb, 0, stream>>>(feat_ref, refT);
    k_w2t<<<144, 256, 0, stream>>>(w2, w2t);

    k_corr_assemble<<<BP_N, 256, 0, stream>>>(featT, refT, alignedT, alignedN);
    k_conv1<<<BP_N / 8, 256, 0, stream>>>(featT, alignedT, w1, b1, h1);
    k_conv2<<<BP_N * 16 / 256, 256, 0, stream>>>(h1, w2t, b2, h2);
    k_conv3<<<BP_N / 256, 256, 0, stream>>>(h2, w3, b3, h3);
    k_score<<<BP_N / 256, 256, 0, stream>>>(h3, w4, b4, sc);
    k_blend<<<(int)(NCP / 256), 256, 0, stream>>>(feat, alignedN, sc, out);
}

// Round 8
// 420.576 us; speedup vs baseline: 1.4311x; 1.4311x over previous
//
#include <hip/hip_runtime.h>
#include <hip/hip_bf16.h>
#include <math.h>

// Problem constants (B=2, C=256, H=W=64, D=4, K=9, K2=81)
#define BATCH 2
#define CCH   256
#define HH    64
#define WW    64
#define PIX   (HH*WW)          // 4096
#define K2    81
#define BP_N  (BATCH*PIX)      // 8192

// ---------------------------------------------------------------------------
// NCHW -> NHWC tiled transpose (per batch).  in: [B][C][P]  out: [B][P][C]
// ---------------------------------------------------------------------------
__global__ void k_transpose(const float* __restrict__ in, float* __restrict__ out) {
    __shared__ float tile[32][33];
    int b  = blockIdx.z;
    int p0 = blockIdx.x * 32;
    int c0 = blockIdx.y * 32;
    int tx = threadIdx.x;     // 32
    int ty = threadIdx.y;     // 8
    const float* ib = in  + (size_t)b * CCH * PIX;
    float*       ob = out + (size_t)b * CCH * PIX;
    #pragma unroll
    for (int i = 0; i < 4; i++) {
        int c = c0 + ty + i * 8;
        int p = p0 + tx;
        tile[ty + i * 8][tx] = ib[(size_t)c * PIX + p];
    }
    __syncthreads();
    #pragma unroll
    for (int i = 0; i < 4; i++) {
        int p = p0 + ty + i * 8;
        int c = c0 + tx;
        ob[(size_t)p * CCH + c] = tile[tx][ty + i * 8];
    }
}

// ---------------------------------------------------------------------------
// Correlation + sum-normalize + assemble — BIT-EXACT recipe (passed R7,
// absmax 16384 / 19988): per-dot 32 strided FMA partials (partial j sums
// c = 32t+j ascending) combined by the tree (p_l+p_{l+8})+(p_{l+16}+p_{l+24})
// -> xor4 -> xor2 -> xor1; k-sum sequential ascending; fp32 divide; assemble
// sequential ascending-k FMA.  DO NOT CHANGE ANY ROUNDING.
//
// R8 perf change (bit-identical math): the 32 partials live one-per-lane in
// a 32-lane half-wave, so phase-1 loads are coalesced (128 B/half-wave)
// instead of 64-way divergent.  The combine tree is exactly the
// xor-{8,16,4,2,1} shuffle butterfly along lane 0's dependency path
// (self-first ordering at every level, verified add-by-add).
// ---------------------------------------------------------------------------
__global__ void k_corr_assemble(const float* __restrict__ featT,
                                const float* __restrict__ refT,
                                float* __restrict__ alignedT,
                                float* __restrict__ alignedN) {
    int bp = blockIdx.x;               // 0..8191
    int b  = bp >> 12;
    int p  = bp & 4095;
    int h  = p >> 6, w = p & 63;
    int tid = threadIdx.x;             // 0..255

    __shared__ float s_feat[256];
    __shared__ float s_aff[K2];
    __shared__ float s_affn[K2];
    __shared__ int   s_pix[K2];
    __shared__ float s_den;

    s_feat[tid] = featT[((size_t)bp << 8) + tid];
    if (tid < K2) {
        int dy = tid / 9, dx = tid - dy * 9;
        int y = h + dy - 4, x = w + dx - 4;
        s_pix[tid] = ((unsigned)y < 64u && (unsigned)x < 64u) ? ((y << 6) | x) : -1;
    }
    __syncthreads();

    const float* rb = refT + ((size_t)b << 20);   // b*4096*256

    // Phase 1: lane-parallel strided partials + butterfly combine.
    // Half-wave hw handles k = 8*it + hw; lane j holds partial j.
    int hw = tid >> 5;        // 0..7
    int j  = tid & 31;        // 0..31
    for (int it = 0; it < 11; it++) {
        int k = it * 8 + hw;
        float partial = 0.f;
        int pix = (k < K2) ? s_pix[k] : -1;
        if (pix >= 0) {
            const float* rp = rb + ((size_t)pix << 8);
            #pragma unroll
            for (int t = 0; t < 8; t++) {
                int c = 32 * t + j;
                partial = fmaf(s_feat[c], rp[c], partial);
            }
        }
        // exact combine tree via xor butterfly (masks < 32 stay in half-wave)
        partial = __fadd_rn(partial, __shfl_xor(partial, 8));
        partial = __fadd_rn(partial, __shfl_xor(partial, 16));
        partial = __fadd_rn(partial, __shfl_xor(partial, 4));
        partial = __fadd_rn(partial, __shfl_xor(partial, 2));
        partial = __fadd_rn(partial, __shfl_xor(partial, 1));
        if (j == 0 && k < K2) s_aff[k] = partial;
    }
    __syncthreads();

    // Phase 2: s = sequential ascending-k fp32 add chain; den = s + 1e-7f
    if (tid == 0) {
        float s = 0.f;
        for (int k = 0; k < K2; k++) s = __fadd_rn(s, s_aff[k]);
        s_den = __fadd_rn(s, 1e-7f);
    }
    __syncthreads();
    if (tid < K2) s_affn[tid] = __fdiv_rn(s_aff[tid], s_den);
    __syncthreads();

    // Phase 3: aligned[c] = sequential ascending-k FMA chain (coalesced)
    int c = tid;
    float acc = 0.f;
    for (int k = 0; k < K2; k++) {
        int pix = s_pix[k];
        if (pix >= 0)
            acc = fmaf(s_affn[k], rb[((size_t)pix << 8) + c], acc);
    }
    alignedT[((size_t)bp << 8) + c] = acc;
    alignedN[((size_t)b << 20) + ((size_t)c << 12) + p] = acc;
}

// ---------------------------------------------------------------------------
// Conv1: 1x1, 512 -> 256, FP32 (numerics-free stage: downstream rounding
// proven irrelevant to absmax in R2-R6).  Block = 256 thr, 8 pixels.
// ---------------------------------------------------------------------------
__global__ void k_conv1(const float* __restrict__ featT,
                        const float* __restrict__ alignedT,
                        const float* __restrict__ w1,
                        const float* __restrict__ b1,
                        float* __restrict__ h1) {
    __shared__ float s_cat[8][512];
    int p0  = blockIdx.x * 8;
    int tid = threadIdx.x;

    for (int i = tid; i < 8 * 512; i += 256) {
        int px = i >> 9;
        int c  = i & 511;
        size_t gp = (size_t)(p0 + px);
        s_cat[px][c] = (c < 256) ? featT[(gp << 8) + c] : alignedT[(gp << 8) + (c - 256)];
    }
    __syncthreads();

    int o = tid;
    float acc[8];
    #pragma unroll
    for (int px = 0; px < 8; px++) acc[px] = 0.f;

    const float* wr = w1 + (size_t)o * 512;
    for (int c = 0; c < 512; c += 4) {
        float4 wv = *(const float4*)(wr + c);
        #pragma unroll
        for (int px = 0; px < 8; px++) {
            float a = acc[px];
            a = fmaf(wv.x, s_cat[px][c + 0], a);
            a = fmaf(wv.y, s_cat[px][c + 1], a);
            a = fmaf(wv.z, s_cat[px][c + 2], a);
            a = fmaf(wv.w, s_cat[px][c + 3], a);
            acc[px] = a;
        }
    }
    float bias = b1[o];
    for (int px = 0; px < 8; px++)
        h1[((size_t)(p0 + px) << 8) + o] = acc[px] + bias;
}

// ---------------------------------------------------------------------------
// w2 [16][256][3][3] (o,c,kk) -> w2t [kk][o][c]  (c contiguous per thread)
// ---------------------------------------------------------------------------
__global__ void k_w2t(const float* __restrict__ w2, float* __restrict__ w2t) {
    int i = blockIdx.x * 256 + threadIdx.x;
    if (i >= 16 * 256 * 9) return;
    int o  = i / 2304;
    int r  = i % 2304;         // c*9 + kk
    int c  = r / 9;
    int kk = r % 9;
    w2t[((size_t)(kk * 16 + o) << 8) + c] = w2[i];
}

// ---------------------------------------------------------------------------
// Conv2: 3x3 pad1, 256 -> 16, FP32, numerics-free.  Thread per (bp, o);
// 4 ILP accumulators, float4 input+weight streams.  h2: [BP][16].
// ---------------------------------------------------------------------------
__global__ void k_conv2(const float* __restrict__ h1,
                        const float* __restrict__ w2t,
                        const float* __restrict__ b2,
                        float* __restrict__ h2) {
    int idx = blockIdx.x * 256 + threadIdx.x;   // bp*16 + o
    int o  = idx & 15;
    int bp = idx >> 4;
    int b  = bp >> 12;
    int p  = bp & 4095;
    int h  = p >> 6, w = p & 63;
    const float* hb = h1 + ((size_t)b << 20);

    float ax = 0.f, ay = 0.f, az = 0.f, aw = 0.f;
    #pragma unroll
    for (int kk = 0; kk < 9; kk++) {
        int ky = kk / 3, kx = kk - ky * 3;
        int y = h + ky - 1, x = w + kx - 1;
        if ((unsigned)y >= 64u || (unsigned)x >= 64u) continue;
        const float* ip = hb + ((size_t)((y << 6) | x) << 8);
        const float* wp = w2t + ((size_t)(kk * 16 + o) << 8);
        #pragma unroll 8
        for (int c = 0; c < 256; c += 4) {
            float4 iv = *(const float4*)(ip + c);
            float4 wv = *(const float4*)(wp + c);
            ax = fmaf(wv.x, iv.x, ax);
            ay = fmaf(wv.y, iv.y, ay);
            az = fmaf(wv.z, iv.z, az);
            aw = fmaf(wv.w, iv.w, aw);
        }
    }
    h2[(size_t)bp * 16 + o] = ((ax + ay) + (az + aw)) + b2[o];
}

// ---------------------------------------------------------------------------
// Conv3: 3x3 pad1, 16 -> 3, FP32, numerics-free.  Thread per pixel.
// ---------------------------------------------------------------------------
__global__ void k_conv3(const float* __restrict__ h2,
                        const float* __restrict__ w3,
                        const float* __restrict__ b3,
                        float* __restrict__ h3) {
    int bp = blockIdx.x * 256 + threadIdx.x;
    if (bp >= BP_N) return;
    int b = bp >> 12;
    int p = bp & 4095;
    int h = p >> 6, w = p & 63;
    const float* hb = h2 + ((size_t)b << 16);   // b*4096*16

    float a0 = 0.f, a1 = 0.f, a2 = 0.f;
    #pragma unroll
    for (int kk = 0; kk < 9; kk++) {
        int ky = kk / 3, kx = kk - ky * 3;
        int y = h + ky - 1, x = w + kx - 1;
        if ((unsigned)y >= 64u || (unsigned)x >= 64u) continue;
        const float* ip = hb + (size_t)((y << 6) | x) * 16;
        #pragma unroll
        for (int c = 0; c < 16; c++) {
            float v = ip[c];
            int wi = c * 9 + kk;
            a0 = fmaf(w3[wi],       v, a0);
            a1 = fmaf(w3[144 + wi], v, a1);
            a2 = fmaf(w3[288 + wi], v, a2);
        }
    }
    h3[(size_t)bp * 3 + 0] = a0 + b3[0];
    h3[(size_t)bp * 3 + 1] = a1 + b3[1];
    h3[(size_t)bp * 3 + 2] = a2 + b3[2];
}

// ---------------------------------------------------------------------------
// Conv4 (3x3, 3 -> 2) + softmax -> (score0, score1), FP32, numerics-free.
// ---------------------------------------------------------------------------
__global__ void k_score(const float* __restrict__ h3,
                        const float* __restrict__ w4,
                        const float* __restrict__ b4,
                        float2* __restrict__ score) {
    int bp = blockIdx.x * 256 + threadIdx.x;
    if (bp >= BP_N) return;
    int b = bp >> 12;
    int p = bp & 4095;
    int h = p >> 6, w = p & 63;
    const float* hb = h3 + (size_t)b * PIX * 3;

    float l0 = 0.f, l1 = 0.f;
    #pragma unroll
    for (int kk = 0; kk < 9; kk++) {
        int ky = kk / 3, kx = kk - ky * 3;
        int y = h + ky - 1, x = w + kx - 1;
        if ((unsigned)y >= 64u || (unsigned)x >= 64u) continue;
        const float* ip = hb + (size_t)((y << 6) | x) * 3;
        #pragma unroll
        for (int c = 0; c < 3; c++) {
            float v = ip[c];
            int wi = c * 9 + kk;
            l0 = fmaf(w4[wi],      v, l0);
            l1 = fmaf(w4[27 + wi], v, l1);
        }
    }
    l0 += b4[0];
    l1 += b4[1];

    float m  = fmaxf(l0, l1);
    float e0 = expf(l0 - m);
    float e1 = expf(l1 - m);
    float s  = e0 + e1;
    score[bp] = make_float2(e0 / s, e1 / s);
}

// ---------------------------------------------------------------------------
// Blend: out = s0*feat + s1*aligned.
// ---------------------------------------------------------------------------
__global__ void k_blend(const float* __restrict__ feat,
                        const float* __restrict__ alignedN,
                        const float2* __restrict__ score,
                        float* __restrict__ out) {
    size_t i = (size_t)blockIdx.x * 256 + threadIdx.x;
    if (i >= (size_t)BATCH * CCH * PIX) return;
    int b = (int)(i >> 20);       // 256*4096 = 2^20
    int p = (int)(i & 4095);
    float2 s = score[(b << 12) + p];
    out[i] = __fadd_rn(__fmul_rn(s.x, feat[i]), __fmul_rn(s.y, alignedN[i]));
}

// ---------------------------------------------------------------------------
extern "C" void kernel_launch(void* const* d_in, const int* in_sizes, int n_in,
                              void* d_out, int out_size, void* d_ws, size_t ws_size,
                              hipStream_t stream) {
    const float* feat     = (const float*)d_in[0];
    const float* feat_ref = (const float*)d_in[1];
    const float* w1 = (const float*)d_in[2];
    const float* b1 = (const float*)d_in[3];
    const float* w2 = (const float*)d_in[4];
    const float* b2 = (const float*)d_in[5];
    const float* w3 = (const float*)d_in[6];
    const float* b3 = (const float*)d_in[7];
    const float* w4 = (const float*)d_in[8];
    const float* b4 = (const float*)d_in[9];
    float* out = (float*)d_out;

    const size_t NCP = (size_t)BATCH * CCH * PIX;   // 2,097,152
    char* wsb = (char*)d_ws;
    float*  featT    = (float*)wsb;   wsb += NCP * 4;               // 8 MB
    float*  refT     = (float*)wsb;   wsb += NCP * 4;               // 8 MB
    float*  alignedT = (float*)wsb;   wsb += NCP * 4;               // 8 MB
    float*  alignedN = (float*)wsb;   wsb += NCP * 4;               // 8 MB
    float*  h1       = (float*)wsb;   wsb += NCP * 4;               // 8 MB
    float*  h2       = (float*)wsb;   wsb += (size_t)BP_N * 16 * 4;
    float*  h3       = (float*)wsb;   wsb += (size_t)BP_N * 3 * 4;
    float2* sc       = (float2*)wsb;  wsb += (size_t)BP_N * 8;
    float*  w2t      = (float*)wsb;   wsb += (size_t)16 * 256 * 9 * 4;

    dim3 tb(32, 8, 1);
    dim3 tg(PIX / 32, CCH / 32, BATCH);
    k_transpose<<<tg, tb, 0, stream>>>(feat, featT);
    k_transpose<<<tg, tb, 0, stream>>>(feat_ref, refT);
    k_w2t<<<144, 256, 0, stream>>>(w2, w2t);

    k_corr_assemble<<<BP_N, 256, 0, stream>>>(featT, refT, alignedT, alignedN);
    k_conv1<<<BP_N / 8, 256, 0, stream>>>(featT, alignedT, w1, b1, h1);
    k_conv2<<<BP_N * 16 / 256, 256, 0, stream>>>(h1, w2t, b2, h2);
    k_conv3<<<BP_N / 256, 256, 0, stream>>>(h2, w3, b3, h3);
    k_score<<<BP_N / 256, 256, 0, stream>>>(h3, w4, b4, sc);
    k_blend<<<(int)(NCP / 256), 256, 0, stream>>>(feat, alignedN, sc, out);
}

// Round 9
// 340.562 us; speedup vs baseline: 1.7674x; 1.2349x over previous
//
#include <hip/hip_runtime.h>
#include <hip/hip_bf16.h>
#include <math.h>

// Problem constants (B=2, C=256, H=W=64, D=4, K=9, K2=81)
#define BATCH 2
#define CCH   256
#define HH    64
#define WW    64
#define PIX   (HH*WW)          // 4096
#define K2    81
#define BP_N  (BATCH*PIX)      // 8192

// ---------------------------------------------------------------------------
// NCHW -> NHWC tiled transpose (per batch).  in: [B][C][P]  out: [B][P][C]
// ---------------------------------------------------------------------------
__global__ void k_transpose(const float* __restrict__ in, float* __restrict__ out) {
    __shared__ float tile[32][33];
    int b  = blockIdx.z;
    int p0 = blockIdx.x * 32;
    int c0 = blockIdx.y * 32;
    int tx = threadIdx.x;     // 32
    int ty = threadIdx.y;     // 8
    const float* ib = in  + (size_t)b * CCH * PIX;
    float*       ob = out + (size_t)b * CCH * PIX;
    #pragma unroll
    for (int i = 0; i < 4; i++) {
        int c = c0 + ty + i * 8;
        int p = p0 + tx;
        tile[ty + i * 8][tx] = ib[(size_t)c * PIX + p];
    }
    __syncthreads();
    #pragma unroll
    for (int i = 0; i < 4; i++) {
        int p = p0 + ty + i * 8;
        int c = c0 + tx;
        ob[(size_t)p * CCH + c] = tile[tx][ty + i * 8];
    }
}

// ---------------------------------------------------------------------------
// Correlation + sum-normalize + assemble — BIT-EXACT recipe (passed R7/R8,
// absmax 16384 / 19988): per-dot 32 strided FMA partials (partial j sums
// c = 32t+j ascending) combined by xor-{8,16,4,2,1} butterfly (== the tree
// (p_l+p_{l+8})+(p_{l+16}+p_{l+24}) -> xor4 -> xor2 -> xor1 along lane 0);
// k-sum sequential ascending; fp32 divide; assemble sequential ascending-k
// FMA.  DO NOT CHANGE ANY ROUNDING.
// ---------------------------------------------------------------------------
__global__ void k_corr_assemble(const float* __restrict__ featT,
                                const float* __restrict__ refT,
                                float* __restrict__ alignedT,
                                float* __restrict__ alignedN) {
    int bp = blockIdx.x;               // 0..8191
    int b  = bp >> 12;
    int p  = bp & 4095;
    int h  = p >> 6, w = p & 63;
    int tid = threadIdx.x;             // 0..255

    __shared__ float s_feat[256];
    __shared__ float s_aff[K2];
    __shared__ float s_affn[K2];
    __shared__ int   s_pix[K2];
    __shared__ float s_den;

    s_feat[tid] = featT[((size_t)bp << 8) + tid];
    if (tid < K2) {
        int dy = tid / 9, dx = tid - dy * 9;
        int y = h + dy - 4, x = w + dx - 4;
        s_pix[tid] = ((unsigned)y < 64u && (unsigned)x < 64u) ? ((y << 6) | x) : -1;
    }
    __syncthreads();

    const float* rb = refT + ((size_t)b << 20);   // b*4096*256

    // Phase 1: lane-parallel strided partials + butterfly combine.
    int hw = tid >> 5;        // 0..7
    int j  = tid & 31;        // 0..31
    for (int it = 0; it < 11; it++) {
        int k = it * 8 + hw;
        float partial = 0.f;
        int pix = (k < K2) ? s_pix[k] : -1;
        if (pix >= 0) {
            const float* rp = rb + ((size_t)pix << 8);
            #pragma unroll
            for (int t = 0; t < 8; t++) {
                int c = 32 * t + j;
                partial = fmaf(s_feat[c], rp[c], partial);
            }
        }
        partial = __fadd_rn(partial, __shfl_xor(partial, 8));
        partial = __fadd_rn(partial, __shfl_xor(partial, 16));
        partial = __fadd_rn(partial, __shfl_xor(partial, 4));
        partial = __fadd_rn(partial, __shfl_xor(partial, 2));
        partial = __fadd_rn(partial, __shfl_xor(partial, 1));
        if (j == 0 && k < K2) s_aff[k] = partial;
    }
    __syncthreads();

    // Phase 2: s = sequential ascending-k fp32 add chain; den = s + 1e-7f
    if (tid == 0) {
        float s = 0.f;
        for (int k = 0; k < K2; k++) s = __fadd_rn(s, s_aff[k]);
        s_den = __fadd_rn(s, 1e-7f);
    }
    __syncthreads();
    if (tid < K2) s_affn[tid] = __fdiv_rn(s_aff[tid], s_den);
    __syncthreads();

    // Phase 3: aligned[c] = sequential ascending-k FMA chain (coalesced)
    int c = tid;
    float acc = 0.f;
    for (int k = 0; k < K2; k++) {
        int pix = s_pix[k];
        if (pix >= 0)
            acc = fmaf(s_affn[k], rb[((size_t)pix << 8) + c], acc);
    }
    alignedT[((size_t)bp << 8) + c] = acc;
    alignedN[((size_t)b << 20) + ((size_t)c << 12) + p] = acc;
}

// ---------------------------------------------------------------------------
// Conv1: 1x1, 512 -> 256, FP32 (numerics-free stage).  Block = 256 thr,
// 8 pixels.  h1: [BP][256] fp32.
// ---------------------------------------------------------------------------
__global__ void k_conv1(const float* __restrict__ featT,
                        const float* __restrict__ alignedT,
                        const float* __restrict__ w1,
                        const float* __restrict__ b1,
                        float* __restrict__ h1) {
    __shared__ float s_cat[8][512];
    int p0  = blockIdx.x * 8;
    int tid = threadIdx.x;

    for (int i = tid; i < 8 * 512; i += 256) {
        int px = i >> 9;
        int c  = i & 511;
        size_t gp = (size_t)(p0 + px);
        s_cat[px][c] = (c < 256) ? featT[(gp << 8) + c] : alignedT[(gp << 8) + (c - 256)];
    }
    __syncthreads();

    int o = tid;
    float acc[8];
    #pragma unroll
    for (int px = 0; px < 8; px++) acc[px] = 0.f;

    const float* wr = w1 + (size_t)o * 512;
    for (int c = 0; c < 512; c += 4) {
        float4 wv = *(const float4*)(wr + c);
        #pragma unroll
        for (int px = 0; px < 8; px++) {
            float a = acc[px];
            a = fmaf(wv.x, s_cat[px][c + 0], a);
            a = fmaf(wv.y, s_cat[px][c + 1], a);
            a = fmaf(wv.z, s_cat[px][c + 2], a);
            a = fmaf(wv.w, s_cat[px][c + 3], a);
            acc[px] = a;
        }
    }
    float bias = b1[o];
    for (int px = 0; px < 8; px++)
        h1[((size_t)(p0 + px) << 8) + o] = acc[px] + bias;
}

// ---------------------------------------------------------------------------
// w2 [16][256][3][3] (o,c,kk) -> w2t [kk][o][c]  (c contiguous per thread)
// ---------------------------------------------------------------------------
__global__ void k_w2t(const float* __restrict__ w2, float* __restrict__ w2t) {
    int i = blockIdx.x * 256 + threadIdx.x;
    if (i >= 16 * 256 * 9) return;
    int o  = i / 2304;
    int r  = i % 2304;         // c*9 + kk
    int c  = r / 9;
    int kk = r % 9;
    w2t[((size_t)(kk * 16 + o) << 8) + c] = w2[i];
}

// ---------------------------------------------------------------------------
// Conv2: 3x3 pad1, 256 -> 16, FP32, numerics-free.  R9 rewrite: tile-GEMM.
// Block = 256 thr = 16 o x 16 pixel-slots, handles 32 pixels (half image row)
// x 16 outputs.  c processed in 4 chunks of 64; the 3x34 pixel halo for the
// chunk is staged in LDS [row][pix][68] (pad 64->68 so the 4 distinct pixel
// addresses per ds_read_b128 hit different banks; the 16 o-lanes per pixel
// read the same address = broadcast, free).  8 independent FMA chains/thread.
// ---------------------------------------------------------------------------
__global__ void k_conv2(const float* __restrict__ h1,
                        const float* __restrict__ w2t,
                        const float* __restrict__ b2,
                        float* __restrict__ h2) {
    __shared__ float s_in[3][34][68];
    int blk = blockIdx.x;          // 0..255
    int b   = blk >> 7;            // 128 half-rows per batch
    int r   = blk & 127;
    int y   = r >> 1;
    int w0  = (r & 1) * 32;
    int tid = threadIdx.x;
    int o   = tid & 15;
    int ps  = tid >> 4;            // 0..15; handles pixels ps and ps+16

    const float* hb = h1 + ((size_t)b << 20);

    float4 a0 = {0.f, 0.f, 0.f, 0.f};
    float4 a1 = {0.f, 0.f, 0.f, 0.f};

    for (int chunk = 0; chunk < 4; chunk++) {
        int c0 = chunk << 6;
        // stage 3 rows x 34 pixels x 64 c (zero-padded at image borders)
        for (int i = tid; i < 3 * 34 * 16; i += 256) {
            int c4 = i & 15;
            int pi = (i >> 4) % 34;
            int ri = (i >> 4) / 34;
            int yy = y + ri - 1;
            int xx = w0 + pi - 1;
            float4 v = {0.f, 0.f, 0.f, 0.f};
            if ((unsigned)yy < 64u && (unsigned)xx < 64u)
                v = *(const float4*)(hb + ((size_t)((yy << 6) | xx) << 8) + c0 + (c4 << 2));
            *(float4*)&s_in[ri][pi][c4 << 2] = v;
        }
        __syncthreads();

        #pragma unroll
        for (int kk = 0; kk < 9; kk++) {
            int ky = kk / 3, kx = kk - ky * 3;
            const float* wp = w2t + (((size_t)(kk * 16 + o)) << 8) + c0;
            #pragma unroll 8
            for (int c4 = 0; c4 < 16; c4++) {
                float4 wv = *(const float4*)(wp + (c4 << 2));
                float4 i0 = *(const float4*)&s_in[ky][ps + kx][c4 << 2];
                float4 i1 = *(const float4*)&s_in[ky][ps + 16 + kx][c4 << 2];
                a0.x = fmaf(wv.x, i0.x, a0.x);
                a0.y = fmaf(wv.y, i0.y, a0.y);
                a0.z = fmaf(wv.z, i0.z, a0.z);
                a0.w = fmaf(wv.w, i0.w, a0.w);
                a1.x = fmaf(wv.x, i1.x, a1.x);
                a1.y = fmaf(wv.y, i1.y, a1.y);
                a1.z = fmaf(wv.z, i1.z, a1.z);
                a1.w = fmaf(wv.w, i1.w, a1.w);
            }
        }
        __syncthreads();
    }

    float bias = b2[o];
    int p0 = (y << 6) + w0;
    size_t bp0 = ((size_t)b << 12) + p0;
    h2[(bp0 + ps) * 16 + o]      = ((a0.x + a0.y) + (a0.z + a0.w)) + bias;
    h2[(bp0 + ps + 16) * 16 + o] = ((a1.x + a1.y) + (a1.z + a1.w)) + bias;
}

// ---------------------------------------------------------------------------
// Conv3: 3x3 pad1, 16 -> 3, FP32, numerics-free.  Thread per pixel.
// ---------------------------------------------------------------------------
__global__ void k_conv3(const float* __restrict__ h2,
                        const float* __restrict__ w3,
                        const float* __restrict__ b3,
                        float* __restrict__ h3) {
    int bp = blockIdx.x * 256 + threadIdx.x;
    if (bp >= BP_N) return;
    int b = bp >> 12;
    int p = bp & 4095;
    int h = p >> 6, w = p & 63;
    const float* hb = h2 + ((size_t)b << 16);   // b*4096*16

    float a0 = 0.f, a1 = 0.f, a2 = 0.f;
    #pragma unroll
    for (int kk = 0; kk < 9; kk++) {
        int ky = kk / 3, kx = kk - ky * 3;
        int y = h + ky - 1, x = w + kx - 1;
        if ((unsigned)y >= 64u || (unsigned)x >= 64u) continue;
        const float* ip = hb + (size_t)((y << 6) | x) * 16;
        #pragma unroll
        for (int c = 0; c < 16; c++) {
            float v = ip[c];
            int wi = c * 9 + kk;
            a0 = fmaf(w3[wi],       v, a0);
            a1 = fmaf(w3[144 + wi], v, a1);
            a2 = fmaf(w3[288 + wi], v, a2);
        }
    }
    h3[(size_t)bp * 3 + 0] = a0 + b3[0];
    h3[(size_t)bp * 3 + 1] = a1 + b3[1];
    h3[(size_t)bp * 3 + 2] = a2 + b3[2];
}

// ---------------------------------------------------------------------------
// Conv4 (3x3, 3 -> 2) + softmax -> (score0, score1), FP32, numerics-free.
// ---------------------------------------------------------------------------
__global__ void k_score(const float* __restrict__ h3,
                        const float* __restrict__ w4,
                        const float* __restrict__ b4,
                        float2* __restrict__ score) {
    int bp = blockIdx.x * 256 + threadIdx.x;
    if (bp >= BP_N) return;
    int b = bp >> 12;
    int p = bp & 4095;
    int h = p >> 6, w = p & 63;
    const float* hb = h3 + (size_t)b * PIX * 3;

    float l0 = 0.f, l1 = 0.f;
    #pragma unroll
    for (int kk = 0; kk < 9; kk++) {
        int ky = kk / 3, kx = kk - ky * 3;
        int y = h + ky - 1, x = w + kx - 1;
        if ((unsigned)y >= 64u || (unsigned)x >= 64u) continue;
        const float* ip = hb + (size_t)((y << 6) | x) * 3;
        #pragma unroll
        for (int c = 0; c < 3; c++) {
            float v = ip[c];
            int wi = c * 9 + kk;
            l0 = fmaf(w4[wi],      v, l0);
            l1 = fmaf(w4[27 + wi], v, l1);
        }
    }
    l0 += b4[0];
    l1 += b4[1];

    float m  = fmaxf(l0, l1);
    float e0 = expf(l0 - m);
    float e1 = expf(l1 - m);
    float s  = e0 + e1;
    score[bp] = make_float2(e0 / s, e1 / s);
}

// ---------------------------------------------------------------------------
// Blend: out = s0*feat + s1*aligned.
// ---------------------------------------------------------------------------
__global__ void k_blend(const float* __restrict__ feat,
                        const float* __restrict__ alignedN,
                        const float2* __restrict__ score,
                        float* __restrict__ out) {
    size_t i = (size_t)blockIdx.x * 256 + threadIdx.x;
    if (i >= (size_t)BATCH * CCH * PIX) return;
    int b = (int)(i >> 20);       // 256*4096 = 2^20
    int p = (int)(i & 4095);
    float2 s = score[(b << 12) + p];
    out[i] = __fadd_rn(__fmul_rn(s.x, feat[i]), __fmul_rn(s.y, alignedN[i]));
}

// ---------------------------------------------------------------------------
extern "C" void kernel_launch(void* const* d_in, const int* in_sizes, int n_in,
                              void* d_out, int out_size, void* d_ws, size_t ws_size,
                              hipStream_t stream) {
    const float* feat     = (const float*)d_in[0];
    const float* feat_ref = (const float*)d_in[1];
    const float* w1 = (const float*)d_in[2];
    const float* b1 = (const float*)d_in[3];
    const float* w2 = (const float*)d_in[4];
    const float* b2 = (const float*)d_in[5];
    const float* w3 = (const float*)d_in[6];
    const float* b3 = (const float*)d_in[7];
    const float* w4 = (const float*)d_in[8];
    const float* b4 = (const float*)d_in[9];
    float* out = (float*)d_out;

    const size_t NCP = (size_t)BATCH * CCH * PIX;   // 2,097,152
    char* wsb = (char*)d_ws;
    float*  featT    = (float*)wsb;   wsb += NCP * 4;               // 8 MB
    float*  refT     = (float*)wsb;   wsb += NCP * 4;               // 8 MB
    float*  alignedT = (float*)wsb;   wsb += NCP * 4;               // 8 MB
    float*  alignedN = (float*)wsb;   wsb += NCP * 4;               // 8 MB
    float*  h1       = (float*)wsb;   wsb += NCP * 4;               // 8 MB
    float*  h2       = (float*)wsb;   wsb += (size_t)BP_N * 16 * 4;
    float*  h3       = (float*)wsb;   wsb += (size_t)BP_N * 3 * 4;
    float2* sc       = (float2*)wsb;  wsb += (size_t)BP_N * 8;
    float*  w2t      = (float*)wsb;   wsb += (size_t)16 * 256 * 9 * 4;

    dim3 tb(32, 8, 1);
    dim3 tg(PIX / 32, CCH / 32, BATCH);
    k_transpose<<<tg, tb, 0, stream>>>(feat, featT);
    k_transpose<<<tg, tb, 0, stream>>>(feat_ref, refT);
    k_w2t<<<144, 256, 0, stream>>>(w2, w2t);

    k_corr_assemble<<<BP_N, 256, 0, stream>>>(featT, refT, alignedT, alignedN);
    k_conv1<<<BP_N / 8, 256, 0, stream>>>(featT, alignedT, w1, b1, h1);
    k_conv2<<<BP_N / 32, 256, 0, stream>>>(h1, w2t, b2, h2);
    k_conv3<<<BP_N / 256, 256, 0, stream>>>(h2, w3, b3, h3);
    k_score<<<BP_N / 256, 256, 0, stream>>>(h3, w4, b4, sc);
    k_blend<<<(int)(NCP / 256), 256, 0, stream>>>(feat, alignedN, sc, out);
}